// Round 14
// baseline (44.941 us; speedup 1.0000x reference)
//
#include <hip/hip_runtime.h>
#include <hip/hip_bf16.h>

// Problem constants
#define IH 4096
#define IW 4096
#define KH 11
#define KW 11
#define OH (IH - KH + 1)   // 4086
#define OW (IW - KW + 1)   // 4086

// Block tile: 64x64 outputs, 4 waves; wave wv owns out rows 16wv..16wv+15.
// Each wave stages its OWN input rows 16wv..16wv+25 (26 x 80) -> no barriers.
#define BM 64
#define BN 64
#define WROWS   26                 // rows staged per wave (16 + 10 halo)
#define TSTRIDE 84                 // LDS row stride in bf16 (proven r11-r13)
#define WTILE   (WROWS * TSTRIDE)  // 2184 shorts = 4368 B per wave
#define NWCHUNK (WROWS * 20)       // 520 float4 chunks per wave (80 cols)
#define WNITER  9                  // ceil(520/64)
#define B_OFF   (4 * WTILE)        // bmat offset: 8736 shorts
// LDS total: 4*4368 + 11*1024 = 28736 B -> 5 blocks/CU

#define TILES_X 64
#define NPAIR   2048               // 2 adjacent-x tiles per block

typedef short bf16x4 __attribute__((ext_vector_type(4)));
typedef short bf16x8 __attribute__((ext_vector_type(8)));
typedef float f32x4  __attribute__((ext_vector_type(4)));

__device__ __forceinline__ short f2b(float f) {
    __hip_bfloat16 h = __float2bfloat16(f);   // RNE
    return __builtin_bit_cast(short, h);
}

// ---- wave-private staging (T14 split: issue early, write late) ----
__device__ __forceinline__ void stage_load(float4 G[WNITER],
                                           const float* __restrict__ x,
                                           int gx0, int gy0w, int lane) {
#pragma unroll
    for (int it = 0; it < WNITER; ++it) {
        const int i = lane + it * 64;
        float4 v = make_float4(0.f, 0.f, 0.f, 0.f);
        if (i < NWCHUNK) {
            const int r  = i / 20;
            const int c4 = i - r * 20;
            const int gy = gy0w + r;
            const int gx = gx0 + c4 * 4;
            if (gy < IH && gx + 3 < IW) {
                v = *reinterpret_cast<const float4*>(x + (size_t)gy * IW + gx);
            }
        }
        G[it] = v;
    }
}

__device__ __forceinline__ void stage_write(short* __restrict__ wb,
                                            const float4 G[WNITER], int lane) {
#pragma unroll
    for (int it = 0; it < WNITER; ++it) {
        const int i = lane + it * 64;
        if (i < NWCHUNK) {
            const int r  = i / 20;
            const int c4 = i - r * 20;
            bf16x4 b = { f2b(G[it].x), f2b(G[it].y), f2b(G[it].z), f2b(G[it].w) };
            *reinterpret_cast<bf16x4*>(&wb[r * TSTRIDE + c4 * 4]) = b;
        }
    }
}

// ---- per-tile MFMA compute (verified rounds 11-13 — unchanged math) ----
// out[oy0+i][ox0+j] = sum_kh sum_k A_kh[i][k]*B_kh[k][j],
// A_kh[i][k] = X[oy0+kh+i][ox0+k], B_kh[k][j] = w[kh][k-j] (banded).
// A row = lane&15, B col = lane&15, C/D col=lane&15,row=(lane>>4)*4+reg.
__device__ __forceinline__ void compute_tile(const short* __restrict__ wb,
                                             const short* __restrict__ bmat,
                                             float bv, float* __restrict__ out,
                                             int gx0, int gy0,
                                             int wv, int g, int li) {
    f32x4 acc[4] = {};
    const short* ap = &wb[li * TSTRIDE + g * 8];      // local row li (+kh)
    const short* bp = &bmat[li * 32 + g * 8];

#pragma unroll 1
    for (int kh = 0; kh < KH; ++kh) {
        const bf16x8 bfrag = *reinterpret_cast<const bf16x8*>(bp + kh * 512);
#pragma unroll
        for (int c = 0; c < 4; ++c) {
            bf16x4 lo = *reinterpret_cast<const bf16x4*>(ap + c * 16);
            bf16x4 hi = *reinterpret_cast<const bf16x4*>(ap + c * 16 + 4);
            bf16x8 a  = __builtin_shufflevector(lo, hi, 0, 1, 2, 3, 4, 5, 6, 7);
            acc[c] = __builtin_amdgcn_mfma_f32_16x16x32_bf16(a, bfrag, acc[c],
                                                             0, 0, 0);
        }
        ap += TSTRIDE;
    }

#pragma unroll
    for (int c = 0; c < 4; ++c) {
        const int ox = gx0 + c * 16 + li;
        if (ox < OW) {
#pragma unroll
            for (int r = 0; r < 4; ++r) {
                const int oy = gy0 + wv * 16 + g * 4 + r;
                if (oy < OH) {
                    out[(size_t)oy * OW + ox] = acc[c][r] + bv;
                }
            }
        }
    }
}

// Barrier-free tile pipeline: each wave stages into its private LDS region
// and free-runs stage->compute->stage across the 2-tile chain. The only
// block-wide barrier is the bmat publish. Waves spread across phases ->
// LDS / HBM / VALU / MFMA overlap via wave-level parallelism.
__global__ __launch_bounds__(256)
void conv2d_mfma_wp(const float* __restrict__ x,
                    const float* __restrict__ w,
                    const float* __restrict__ bias,
                    float* __restrict__ out) {
    __shared__ short lds[B_OFF + KH * 512];   // 28736 B

    const int tid = threadIdx.x;
    // XCD-bijective swizzle (2048 % 8 == 0): each XCD gets 256 contiguous
    // pairs = 8 full tile rows -> halo re-reads hit the same L2.
    const int pair = (blockIdx.x & 7) * (NPAIR / 8) + (blockIdx.x >> 3);
    const int t0   = pair * 2;               // even -> t0,t0+1 share a row
    const int gy0  = (t0 >> 6) * BM;
    const int gxb  = (t0 & (TILES_X - 1)) * BN;

    const int lane = tid & 63;
    const int wv   = tid >> 6;
    const int g    = lane >> 4;
    const int li   = lane & 15;
    const int gy0w = gy0 + 16 * wv;          // this wave's first input row
    short* wb = &lds[wv * WTILE];            // wave-private region
    const short* bmat = &lds[B_OFF];
    const float bv = bias[0];

    // ---- Prologue: build B matrices (all threads), stage tile 0 ----
#pragma unroll
    for (int t = 0; t < 22; ++t) {             // 22*256 = 5632 exact
        const int idx = tid + t * 256;
        const int kh = idx >> 9;
        const int j  = (idx >> 5) & 15;
        const int k  = idx & 31;
        const int d  = k - j;
        const float val = (d >= 0 && d < KW) ? w[kh * KW + d] : 0.f;
        lds[B_OFF + idx] = f2b(val);
    }
    {
        float4 G0[WNITER];
        stage_load(G0, x, gxb, gy0w, lane);
        stage_write(wb, G0, lane);
    }
    __syncthreads();   // publish bmat (also the last block-wide sync)

    // ---- Tile 0: prefetch tile 1's rows, compute, write, compute ----
    float4 G[WNITER];
    stage_load(G, x, gxb + BN, gy0w, lane);
    __builtin_amdgcn_sched_barrier(0);       // keep loads above compute

    compute_tile(wb, bmat, bv, out, gxb, gy0, wv, g, li);

    stage_write(wb, G, lane);                // wave-ordered DS: no barrier
    compute_tile(wb, bmat, bv, out, gxb + BN, gy0, wv, g, li);
}

extern "C" void kernel_launch(void* const* d_in, const int* in_sizes, int n_in,
                              void* d_out, int out_size, void* d_ws, size_t ws_size,
                              hipStream_t stream) {
    const float* x    = (const float*)d_in[0];
    const float* w    = (const float*)d_in[1];
    const float* bias = (const float*)d_in[2];
    float* out        = (float*)d_out;

    dim3 grid(NPAIR);     // 2048 blocks x 2 tiles
    dim3 block(256);
    conv2d_mfma_wp<<<grid, block, 0, stream>>>(x, w, bias, out);
}

// Round 15
// 38.330 us; speedup vs baseline: 1.1725x; 1.1725x over previous
//
#include <hip/hip_runtime.h>
#include <hip/hip_bf16.h>

// Problem constants
#define IH 4096
#define IW 4096
#define KH 11
#define KW 11
#define OH (IH - KH + 1)   // 4086
#define OW (IW - KW + 1)   // 4086

// Block tile: 64x64 outputs, 4 waves; wave wv -> rows 16wv..16wv+15
#define BM 64
#define BN 64
#define TROWS   74          // staged input rows (64 + 10 halo)
#define TSTRIDE 84          // LDS row stride in bf16 (proven low-conflict r11-r13)
#define NC4     20          // float4 chunks per staged row (80 floats)
#define NCHUNK  (TROWS * NC4)      // 1480
#define NITER   6                  // ceil(1480/256)
#define TILE_SHORTS (TROWS * TSTRIDE)  // 6216

#define TILES_X 64
#define NBLK    1024        // 4 adjacent-x tiles per block

typedef short bf16x4 __attribute__((ext_vector_type(4)));
typedef short bf16x8 __attribute__((ext_vector_type(8)));
typedef float f32x4  __attribute__((ext_vector_type(4)));

__device__ __forceinline__ short f2b(float f) {
    __hip_bfloat16 h = __float2bfloat16(f);   // RNE
    return __builtin_bit_cast(short, h);
}

// ---- staging split (T14): issue global loads early, LDS-write late ----
__device__ __forceinline__ void stage_load(float4 G[NITER],
                                           const float* __restrict__ x,
                                           int gx0, int gy0, int tid) {
#pragma unroll
    for (int it = 0; it < NITER; ++it) {
        const int i = tid + it * 256;
        float4 v = make_float4(0.f, 0.f, 0.f, 0.f);
        if (i < NCHUNK) {
            const int r  = i / NC4;
            const int c4 = i - r * NC4;
            const int gy = gy0 + r;
            const int gx = gx0 + c4 * 4;
            if (gy < IH && gx + 3 < IW) {
                v = *reinterpret_cast<const float4*>(x + (size_t)gy * IW + gx);
            }
        }
        G[it] = v;
    }
}

__device__ __forceinline__ void stage_write(short* __restrict__ tb,
                                            const float4 G[NITER], int tid) {
#pragma unroll
    for (int it = 0; it < NITER; ++it) {
        const int i = tid + it * 256;
        if (i < NCHUNK) {
            const int r  = i / NC4;
            const int c4 = i - r * NC4;
            bf16x4 b = { f2b(G[it].x), f2b(G[it].y), f2b(G[it].z), f2b(G[it].w) };
            *reinterpret_cast<bf16x4*>(&tb[r * TSTRIDE + c4 * 4]) = b;
        }
    }
}

// ---- fragment helpers ----
__device__ __forceinline__ void loadA(bf16x8 a[4], const short* __restrict__ ap) {
#pragma unroll
    for (int c = 0; c < 4; ++c) {
        bf16x4 lo = *reinterpret_cast<const bf16x4*>(ap + c * 16);
        bf16x4 hi = *reinterpret_cast<const bf16x4*>(ap + c * 16 + 4);
        a[c] = __builtin_shufflevector(lo, hi, 0, 1, 2, 3, 4, 5, 6, 7);
    }
}

__device__ __forceinline__ void mfma4(f32x4 acc[4], const bf16x8 a[4], bf16x8 b) {
#pragma unroll
    for (int c = 0; c < 4; ++c) {
        acc[c] = __builtin_amdgcn_mfma_f32_16x16x32_bf16(a[c], b, acc[c], 0, 0, 0);
    }
}

// ---- per-tile MFMA compute, software-pipelined over kh ----
// Math identical to rounds 11-14 (verified): out = sum_kh A_kh * B_kh,
// A_kh[i][k] = X[oy0+kh+i][ox0+k], B_kh[k][j] = w[kh][k-j] (banded).
// Pipeline: static even/odd fragment buffers; loads for kh+1 issue BEFORE
// the MFMAs of kh, so the ~120cy LDS latency hides under MFMA issue.
// Static naming (Ae/Ao) avoids dynamic reg-array indexing (rule #20) and
// bounds the live set (~100 regs) — the rounds-0-5 balloon lesson.
__device__ __forceinline__ void compute_tile(const short* __restrict__ tb,
                                             const short* __restrict__ bmat,
                                             float bv, float* __restrict__ out,
                                             int gx0, int gy0,
                                             int wv, int g, int li) {
    f32x4 acc[4] = {};
    const short* ap = &tb[(16 * wv + li) * TSTRIDE + g * 8];
    const short* bp = &bmat[li * 32 + g * 8];

    bf16x8 Ae[4], Ao[4], Be, Bo;
    loadA(Ae, ap);                                        // kh = 0
    Be = *reinterpret_cast<const bf16x8*>(bp);

#pragma unroll 1
    for (int kh2 = 0; kh2 < 5; ++kh2) {
        loadA(Ao, ap + TSTRIDE);                          // kh odd
        Bo = *reinterpret_cast<const bf16x8*>(bp + 512);
        mfma4(acc, Ae, Be);                               // compute even
        ap += 2 * TSTRIDE;
        bp += 1024;
        loadA(Ae, ap);                                    // kh next even
        Be = *reinterpret_cast<const bf16x8*>(bp);
        mfma4(acc, Ao, Bo);                               // compute odd
    }
    mfma4(acc, Ae, Be);                                   // kh = 10

#pragma unroll
    for (int c = 0; c < 4; ++c) {
        const int ox = gx0 + c * 16 + li;
        if (ox < OW) {
#pragma unroll
            for (int r = 0; r < 4; ++r) {
                const int oy = gy0 + wv * 16 + g * 4 + r;
                if (oy < OH) {
                    out[(size_t)oy * OW + ox] = acc[c][r] + bv;
                }
            }
        }
    }
}

// Persistent 4-tile chain with double-buffered input tile (round-13 chassis):
//   stage_load(t+1) -> compute(buf[t&1]) -> stage_write(buf[t^1]) -> barrier
__global__ __launch_bounds__(256)
void conv2d_mfma5(const float* __restrict__ x,
                  const float* __restrict__ w,
                  const float* __restrict__ bias,
                  float* __restrict__ out) {
    __shared__ short buf[2][TILE_SHORTS];   // 2 x 12432 B
    __shared__ short bmat[KH * 512];        // 11264 B  (total 36128 B)

    const int tid = threadIdx.x;
    // XCD-bijective swizzle (1024 % 8 == 0): each XCD gets 128 contiguous
    // blocks = 8 full tile rows -> x/y halo re-reads hit the same L2.
    const int blk = (blockIdx.x & 7) * (NBLK / 8) + (blockIdx.x >> 3);
    const int t0  = blk * 4;                 // 4 adjacent-x tiles, same row
    const int gy0 = (t0 >> 6) * BM;
    const int gxb = (t0 & (TILES_X - 1)) * BN;

    const int lane = tid & 63;
    const int wv   = tid >> 6;
    const int g    = lane >> 4;
    const int li   = lane & 15;
    const float bv = bias[0];

    // Prologue: stage tile 0 + build B matrices.
    {
        float4 G0[NITER];
        stage_load(G0, x, gxb, gy0, tid);
        stage_write(buf[0], G0, tid);
    }
#pragma unroll
    for (int t = 0; t < 22; ++t) {             // 22*256 = 5632 exact
        const int idx = tid + t * 256;
        const int kh = idx >> 9;
        const int j  = (idx >> 5) & 15;
        const int k  = idx & 31;
        const int d  = k - j;
        const float val = (d >= 0 && d < KW) ? w[kh * KW + d] : 0.f;
        bmat[idx] = f2b(val);
    }
    __syncthreads();

    float4 G[NITER];
#pragma unroll 1
    for (int t = 0; t < 4; ++t) {
        if (t < 3) {
            stage_load(G, x, gxb + (t + 1) * BN, gy0, tid);
            __builtin_amdgcn_sched_barrier(0);   // keep loads above compute
        }
        compute_tile(buf[t & 1], bmat, bv, out, gxb + t * BN, gy0, wv, g, li);
        if (t < 3) {
            stage_write(buf[(t + 1) & 1], G, tid);
            __syncthreads();                     // publish tile t+1
        }
    }
}

extern "C" void kernel_launch(void* const* d_in, const int* in_sizes, int n_in,
                              void* d_out, int out_size, void* d_ws, size_t ws_size,
                              hipStream_t stream) {
    const float* x    = (const float*)d_in[0];
    const float* w    = (const float*)d_in[1];
    const float* bias = (const float*)d_in[2];
    float* out        = (float*)d_out;

    dim3 grid(NBLK);      // 1024 blocks x 4 tiles
    dim3 block(256);
    conv2d_mfma5<<<grid, block, 0, stream>>>(x, w, bias, out);
}